// Round 3
// baseline (39.875 us; speedup 1.0000x reference)
//
#include <hip/hip_runtime.h>

#define BATCH   65536
#define NREL    100
#define BCAP    1024          // bucket capacity per relation (mean 655, 14-sigma safe)
#define NTILE   (BCAP / 64)   // 16 tiles of 64 elements per relation
#define DSTR    68            // LDS row stride: 68*4B = 272B, 16B-aligned, 2-way banks (free)

// ---- Kernel 1: bucket batch indices by relation ---------------------------
// 256 blocks x 256 threads, 1 element/thread. LDS histogram -> one global
// atomicAdd per (block, relation) to reserve a range -> scatter. Bucket order
// is non-deterministic but out[b] depends only on b's own data, so the final
// output is bit-identical across runs.
__launch_bounds__(256)
__global__ void transr_bucket(const int* __restrict__ relation,
                              int* __restrict__ gcnt,
                              int* __restrict__ bucket) {
    __shared__ int hist[NREL];
    __shared__ int base_s[NREL];
    const int tid = threadIdx.x;

    for (int r = tid; r < NREL; r += 256) hist[r] = 0;
    __syncthreads();

    const int i   = blockIdx.x * 256 + tid;
    const int rel = relation[i];
    const int lr  = atomicAdd(&hist[rel], 1);   // local rank within block
    __syncthreads();

    for (int r = tid; r < NREL; r += 256)
        base_s[r] = hist[r] ? atomicAdd(&gcnt[r], hist[r]) : 0;
    __syncthreads();

    bucket[rel * BCAP + base_s[rel] + lr] = i;
}

// ---- Kernel 2: per-(relation, 64-elem tile) matvec + score ----------------
// 4 waves/block; wave = 16-column quarter of the 64x64 projection.
// Gather d = h-t cooperatively (coalesced, 4 threads/row) into LDS, pull each
// lane's row into registers (static indexing), then a fully-unrolled 64x16
// FMA loop: v_fmac_f32 acc, s_P, v_d with s_load_dwordx16 P rows. No LDS in
// the hot loop.
__launch_bounds__(256, 4)
__global__ void transr_compute(const int* __restrict__ head,
                               const int* __restrict__ tail,
                               const float* __restrict__ ent,
                               const float* __restrict__ remb,
                               const float* __restrict__ proj,
                               const int* __restrict__ gcnt,
                               const int* __restrict__ bucket,
                               float* __restrict__ out) {
    __shared__ float dstage[64 * DSTR];
    __shared__ float psum[4][64];

    const int tid   = threadIdx.x;
    const int wid   = tid >> 6;
    const int lane  = tid & 63;
    const int rel   = blockIdx.y;
    const int start = blockIdx.x << 6;
    const int cnt   = gcnt[rel];
    if (start >= cnt) return;               // uniform early-exit, empty tile

    // cooperative gather: thread = (elem = tid>>2, quarter q = tid&3)
    {
        const int elem = tid >> 2, q = tid & 3;
        const int j  = start + elem;
        const int jj = (j < cnt) ? j : (cnt - 1);
        const int b  = bucket[rel * BCAP + jj];
        const int h  = head[b], t = tail[b];
        const float4* h4 = (const float4*)(ent + (size_t)h * 64) + q * 4;
        const float4* t4 = (const float4*)(ent + (size_t)t * 64) + q * 4;
        #pragma unroll
        for (int k = 0; k < 4; ++k) {
            float4 a = h4[k], c = t4[k];
            float* ds = &dstage[elem * DSTR + q * 16 + k * 4];
            ds[0] = a.x - c.x; ds[1] = a.y - c.y;
            ds[2] = a.z - c.z; ds[3] = a.w - c.w;
        }
    }

    // wave-uniform scalar bases -> s_load path; remb folded into acc init
    const int coloff = __builtin_amdgcn_readfirstlane(wid << 4);
    const float* Pq  = proj + (size_t)rel * 4096 + coloff;
    const float* Rq  = remb + rel * 64 + coloff;
    float acc[16];
    #pragma unroll
    for (int r = 0; r < 16; ++r) acc[r] = Rq[r];

    __syncthreads();

    // pull this lane's d row into registers (16B-aligned b128 reads, 2-way banks)
    float dreg[64];
    #pragma unroll
    for (int k = 0; k < 16; ++k) {
        float4 v = *(const float4*)&dstage[lane * DSTR + 4 * k];
        dreg[4*k+0] = v.x; dreg[4*k+1] = v.y;
        dreg[4*k+2] = v.z; dreg[4*k+3] = v.w;
    }

    // fully-unrolled 64x16: pure v_fmac with SGPR operand (static dreg index)
    #pragma unroll
    for (int e = 0; e < 64; ++e) {
        const float* Pe = Pq + (e << 6);
        #pragma unroll
        for (int r = 0; r < 16; ++r) acc[r] = fmaf(dreg[e], Pe[r], acc[r]);
    }

    float s0 = 0.f, s1 = 0.f;
    #pragma unroll
    for (int r = 0; r < 16; r += 2) {
        s0 = fmaf(acc[r],     acc[r],     s0);
        s1 = fmaf(acc[r + 1], acc[r + 1], s1);
    }
    psum[wid][lane] = s0 + s1;
    __syncthreads();

    if (wid == 0) {
        const int j = start + lane;
        if (j < cnt) {
            const int b = bucket[rel * BCAP + j];
            out[b] = (psum[0][lane] + psum[1][lane]) +
                     (psum[2][lane] + psum[3][lane]);
        }
    }
}

extern "C" void kernel_launch(void* const* d_in, const int* in_sizes, int n_in,
                              void* d_out, int out_size, void* d_ws, size_t ws_size,
                              hipStream_t stream) {
    const int*   head     = (const int*)d_in[0];
    const int*   relation = (const int*)d_in[1];
    const int*   tail     = (const int*)d_in[2];
    const float* ent      = (const float*)d_in[3];
    const float* remb     = (const float*)d_in[4];
    const float* proj     = (const float*)d_in[5];
    float*       out      = (float*)d_out;

    int* gcnt   = (int*)d_ws;                 // 100 ints
    int* bucket = (int*)d_ws + 256;           // offset 1KB; 100*1024 ints

    hipMemsetAsync(d_ws, 0, NREL * sizeof(int), stream);   // zero counters each call
    transr_bucket<<<BATCH / 256, 256, 0, stream>>>(relation, gcnt, bucket);
    transr_compute<<<dim3(NTILE, NREL), 256, 0, stream>>>(
        head, tail, ent, remb, proj, gcnt, bucket, out);
}

// Round 4
// 33.571 us; speedup vs baseline: 1.1878x; 1.1878x over previous
//
#include <hip/hip_runtime.h>

#define BATCH   65536
#define NREL    100
#define BCAP    1024          // bucket capacity per relation (mean 655, 14-sigma safe)
#define NTILE   (BCAP / 64)   // 16 tiles of 64 elements per relation
#define DSTR    68            // LDS row stride: 272B, 16B-aligned, 2-way banks (free)

// ---- Kernel 1: bucket batch indices by relation ---------------------------
// 64 blocks x 256 threads x 4 elements (int4 load). LDS histogram -> one
// global atomicAdd per (block, relation) -> scatter. Bucket order is
// non-deterministic but out[b] depends only on b's own data, so the final
// output is bit-identical across runs.
__launch_bounds__(256)
__global__ void transr_bucket(const int* __restrict__ relation,
                              int* __restrict__ gcnt,
                              int* __restrict__ bucket) {
    __shared__ int hist[NREL];
    __shared__ int base_s[NREL];
    const int tid = threadIdx.x;

    for (int r = tid; r < NREL; r += 256) hist[r] = 0;
    __syncthreads();

    const int4 v = ((const int4*)relation)[blockIdx.x * 256 + tid];
    const int vals[4] = {v.x, v.y, v.z, v.w};
    int lr[4];
    #pragma unroll
    for (int k = 0; k < 4; ++k) lr[k] = atomicAdd(&hist[vals[k]], 1);
    __syncthreads();

    for (int r = tid; r < NREL; r += 256)
        base_s[r] = hist[r] ? atomicAdd(&gcnt[r], hist[r]) : 0;
    __syncthreads();

    const int i0 = (blockIdx.x * 256 + tid) * 4;
    #pragma unroll
    for (int k = 0; k < 4; ++k)
        bucket[vals[k] * BCAP + base_s[vals[k]] + lr[k]] = i0 + k;
}

// ---- Kernel 2: per-(relation, 64-elem tile) matvec + score ----------------
// 4 waves/block; wave = 16-column quarter of the 64x64 projection.
// Round-2-proven inner loop: d staged in LDS (lane-private, stride 68),
// #pragma unroll 4 keeps 4 s_load_dwordx16 P-rows in flight, FMA reads the
// P operand directly from SGPRs. No forced occupancy bound -> no spills.
__launch_bounds__(256)
__global__ void transr_compute(const int* __restrict__ head,
                               const int* __restrict__ tail,
                               const float* __restrict__ ent,
                               const float* __restrict__ remb,
                               const float* __restrict__ proj,
                               const int* __restrict__ gcnt,
                               const int* __restrict__ bucket,
                               float* __restrict__ out) {
    __shared__ float dstage[64 * DSTR];
    __shared__ float psum[4][64];

    const int tid   = threadIdx.x;
    const int wid   = tid >> 6;
    const int lane  = tid & 63;
    const int rel   = blockIdx.y;
    const int start = blockIdx.x << 6;
    const int cnt   = gcnt[rel];
    if (start >= cnt) return;               // uniform early-exit, empty tile

    // cooperative gather: thread = (elem = tid>>2, quarter q = tid&3)
    {
        const int elem = tid >> 2, q = tid & 3;
        const int j  = start + elem;
        const int jj = (j < cnt) ? j : (cnt - 1);
        const int b  = bucket[rel * BCAP + jj];
        const int h  = head[b], t = tail[b];
        const float4* h4 = (const float4*)(ent + (size_t)h * 64) + q * 4;
        const float4* t4 = (const float4*)(ent + (size_t)t * 64) + q * 4;
        #pragma unroll
        for (int k = 0; k < 4; ++k) {
            float4 a = h4[k], c = t4[k];
            float* ds = &dstage[elem * DSTR + q * 16 + k * 4];
            ds[0] = a.x - c.x; ds[1] = a.y - c.y;
            ds[2] = a.z - c.z; ds[3] = a.w - c.w;
        }
    }

    // wave-uniform scalar bases -> s_load path; remb folded into acc init
    const int coloff = __builtin_amdgcn_readfirstlane(wid << 4);
    const float* Pq  = proj + (size_t)rel * 4096 + coloff;
    const float* Rq  = remb + rel * 64 + coloff;
    float acc[16];
    #pragma unroll
    for (int r = 0; r < 16; ++r) acc[r] = Rq[r];

    __syncthreads();

    // 64x16 matvec: lane-private LDS read of d[e] + 16 FMA with SGPR operand
    #pragma unroll 4
    for (int e = 0; e < 64; ++e) {
        const float de = dstage[lane * DSTR + e];
        const float* Pe = Pq + (e << 6);     // wave-uniform -> s_load_dwordx16
        #pragma unroll
        for (int r = 0; r < 16; ++r) acc[r] = fmaf(de, Pe[r], acc[r]);
    }

    float s0 = 0.f, s1 = 0.f;
    #pragma unroll
    for (int r = 0; r < 16; r += 2) {
        s0 = fmaf(acc[r],     acc[r],     s0);
        s1 = fmaf(acc[r + 1], acc[r + 1], s1);
    }
    psum[wid][lane] = s0 + s1;
    __syncthreads();

    if (wid == 0) {
        const int j = start + lane;
        if (j < cnt) {
            const int b = bucket[rel * BCAP + j];
            out[b] = (psum[0][lane] + psum[1][lane]) +
                     (psum[2][lane] + psum[3][lane]);
        }
    }
}

extern "C" void kernel_launch(void* const* d_in, const int* in_sizes, int n_in,
                              void* d_out, int out_size, void* d_ws, size_t ws_size,
                              hipStream_t stream) {
    const int*   head     = (const int*)d_in[0];
    const int*   relation = (const int*)d_in[1];
    const int*   tail     = (const int*)d_in[2];
    const float* ent      = (const float*)d_in[3];
    const float* remb     = (const float*)d_in[4];
    const float* proj     = (const float*)d_in[5];
    float*       out      = (float*)d_out;

    int* gcnt   = (int*)d_ws;                 // 100 ints
    int* bucket = (int*)d_ws + 256;           // offset 1KB; 100*1024 ints

    hipMemsetAsync(d_ws, 0, NREL * sizeof(int), stream);   // zero counters each call
    transr_bucket<<<BATCH / 1024, 256, 0, stream>>>(relation, gcnt, bucket);
    transr_compute<<<dim3(NTILE, NREL), 256, 0, stream>>>(
        head, tail, ent, remb, proj, gcnt, bucket, out);
}

// Round 5
// 26.056 us; speedup vs baseline: 1.5304x; 1.2884x over previous
//
#include <hip/hip_runtime.h>

#define BATCH   65536
#define NREL    100
#define BCAP    1024          // bucket capacity per relation (mean 655, 14-sigma safe)
#define NTILE   (BCAP / 64)   // 16 tiles of 64 rows per relation

typedef __attribute__((ext_vector_type(8))) short bf16x8;
typedef __attribute__((ext_vector_type(4))) float f32x4;

__device__ __forceinline__ unsigned short f2bf(float x) {   // RNE f32->bf16
    unsigned u = __float_as_uint(x);
    u += 0x7fffu + ((u >> 16) & 1u);
    return (unsigned short)(u >> 16);
}

// ---- Kernel 1: bucket batch indices by relation (unchanged, proven) -------
__launch_bounds__(256)
__global__ void transr_bucket(const int* __restrict__ relation,
                              int* __restrict__ gcnt,
                              int* __restrict__ bucket) {
    __shared__ int hist[NREL];
    __shared__ int base_s[NREL];
    const int tid = threadIdx.x;

    for (int r = tid; r < NREL; r += 256) hist[r] = 0;
    __syncthreads();

    const int4 v = ((const int4*)relation)[blockIdx.x * 256 + tid];
    const int vals[4] = {v.x, v.y, v.z, v.w};
    int lr[4];
    #pragma unroll
    for (int k = 0; k < 4; ++k) lr[k] = atomicAdd(&hist[vals[k]], 1);
    __syncthreads();

    for (int r = tid; r < NREL; r += 256)
        base_s[r] = hist[r] ? atomicAdd(&gcnt[r], hist[r]) : 0;
    __syncthreads();

    const int i0 = (blockIdx.x * 256 + tid) * 4;
    #pragma unroll
    for (int k = 0; k < 4; ++k)
        bucket[vals[k] * BCAP + base_s[vals[k]] + lr[k]] = i0 + k;
}

// ---- Kernel 2: MFMA per-(relation, 64-row tile) ---------------------------
// Block = 4 waves. Stage D-tile (64x64 d=h-t, bf16) and P^T-tile (bf16) in
// LDS with XOR-swizzled 16B slices (conflict-free b128 frag reads). Wave w
// computes C rows w*16..w*16+15 via 2 k-steps x 4 n-tiles of
// mfma_f32_16x16x32_bf16, remb folded into acc init. Epilogue: square,
// shfl_xor row-reduce, scattered store via bucket list.
// Fragment layout (gfx950 16x16x32): A: lane l holds A[l&15][(l>>4)*8+j];
// B: lane l holds B[(l>>4)*8+j][l&15]; C/D: col=l&15, row=(l>>4)*4+reg (m89).
__launch_bounds__(256)
__global__ void transr_compute(const int* __restrict__ head,
                               const int* __restrict__ tail,
                               const float* __restrict__ ent,
                               const float* __restrict__ remb,
                               const float* __restrict__ proj,
                               const int* __restrict__ gcnt,
                               const int* __restrict__ bucket,
                               float* __restrict__ out) {
    __shared__ unsigned short Abuf[64 * 64];   // D rows, [row][k] swizzled
    __shared__ unsigned short Bbuf[64 * 64];   // P^T,   [n][k]  swizzled
    __shared__ float remb_s[64];

    const int tid   = threadIdx.x;
    const int wid   = tid >> 6;
    const int lane  = tid & 63;
    const int rel   = blockIdx.y;
    const int start = blockIdx.x << 6;
    const int cnt   = gcnt[rel];
    if (start >= cnt) return;

    if (tid < 64) remb_s[tid] = remb[rel * 64 + tid];

    // ---- stage A: thread = (row = tid>>2, quarter q = tid&3), 16 k's each
    {
        const int row = tid >> 2, q = tid & 3;
        const int j  = start + row;
        const int jj = (j < cnt) ? j : (cnt - 1);
        const int b  = bucket[rel * BCAP + jj];
        const int h  = head[b], t = tail[b];
        const float4* h4 = (const float4*)(ent + (size_t)h * 64) + q * 4;
        const float4* t4 = (const float4*)(ent + (size_t)t * 64) + q * 4;
        #pragma unroll
        for (int i = 0; i < 2; ++i) {          // two 16B bf16 slices
            unsigned short u[8];
            #pragma unroll
            for (int m = 0; m < 2; ++m) {
                float4 a = h4[i * 2 + m], c = t4[i * 2 + m];
                u[m * 4 + 0] = f2bf(a.x - c.x);
                u[m * 4 + 1] = f2bf(a.y - c.y);
                u[m * 4 + 2] = f2bf(a.z - c.z);
                u[m * 4 + 3] = f2bf(a.w - c.w);
            }
            const int slice = (q * 2 + i) ^ (row & 7);   // XOR swizzle
            *(bf16x8*)&Abuf[row * 64 + slice * 8] = *(bf16x8*)u;
        }
    }

    // ---- stage B^T: thread = (k = tid>>2, q = tid&3) reads P[k][q*16..+15]
    {
        const int k = tid >> 2, q = tid & 3;
        const float4* p4 = (const float4*)(proj + (size_t)rel * 4096 + k * 64 + q * 16);
        const int khi = k >> 3, klo = k & 7;
        #pragma unroll
        for (int m = 0; m < 4; ++m) {
            float4 v = p4[m];
            const float vv[4] = {v.x, v.y, v.z, v.w};
            #pragma unroll
            for (int jj2 = 0; jj2 < 4; ++jj2) {
                const int n = q * 16 + m * 4 + jj2;
                Bbuf[n * 64 + ((khi ^ (n & 7)) * 8) + klo] = f2bf(vv[jj2]);
            }
        }
    }
    __syncthreads();

    // ---- MFMA: wave strip = rows wid*16..+15; 2 k-steps x 4 n-tiles
    const int arow = wid * 16 + (lane & 15);
    const int g    = lane >> 4;

    f32x4 acc[4];
    #pragma unroll
    for (int f = 0; f < 4; ++f) {
        const float rv = remb_s[f * 16 + (lane & 15)];   // fold remb into C init
        acc[f] = (f32x4){rv, rv, rv, rv};
    }

    #pragma unroll
    for (int s = 0; s < 2; ++s) {
        const int ks = g + s * 4;
        bf16x8 av = *(const bf16x8*)&Abuf[arow * 64 + ((ks ^ (arow & 7)) * 8)];
        #pragma unroll
        for (int f = 0; f < 4; ++f) {
            const int col = f * 16 + (lane & 15);
            bf16x8 bv = *(const bf16x8*)&Bbuf[col * 64 + ((ks ^ (col & 7)) * 8)];
            acc[f] = __builtin_amdgcn_mfma_f32_16x16x32_bf16(av, bv, acc[f], 0, 0, 0);
        }
    }

    // ---- epilogue: score[row] = sum_col acc^2 ; reduce across 16 col-lanes
    float ps[4];
    #pragma unroll
    for (int r = 0; r < 4; ++r) {
        ps[r] = acc[0][r] * acc[0][r] + acc[1][r] * acc[1][r] +
                acc[2][r] * acc[2][r] + acc[3][r] * acc[3][r];
    }
    #pragma unroll
    for (int m = 1; m < 16; m <<= 1) {
        #pragma unroll
        for (int r = 0; r < 4; ++r) ps[r] += __shfl_xor(ps[r], m, 64);
    }

    if ((lane & 15) == 0) {
        const int rowbase = start + wid * 16 + g * 4;
        #pragma unroll
        for (int r = 0; r < 4; ++r) {
            const int j = rowbase + r;
            if (j < cnt) out[bucket[rel * BCAP + j]] = ps[r];
        }
    }
}

extern "C" void kernel_launch(void* const* d_in, const int* in_sizes, int n_in,
                              void* d_out, int out_size, void* d_ws, size_t ws_size,
                              hipStream_t stream) {
    const int*   head     = (const int*)d_in[0];
    const int*   relation = (const int*)d_in[1];
    const int*   tail     = (const int*)d_in[2];
    const float* ent      = (const float*)d_in[3];
    const float* remb     = (const float*)d_in[4];
    const float* proj     = (const float*)d_in[5];
    float*       out      = (float*)d_out;

    int* gcnt   = (int*)d_ws;                 // 100 ints
    int* bucket = (int*)d_ws + 256;           // offset 1KB; 100*1024 ints

    hipMemsetAsync(d_ws, 0, NREL * sizeof(int), stream);
    transr_bucket<<<BATCH / 1024, 256, 0, stream>>>(relation, gcnt, bucket);
    transr_compute<<<dim3(NTILE, NREL), 256, 0, stream>>>(
        head, tail, ent, remb, proj, gcnt, bucket, out);
}

// Round 7
// 22.721 us; speedup vs baseline: 1.7550x; 1.1468x over previous
//
#include <hip/hip_runtime.h>

#define BATCH   65536
#define NREL    100
#define NBB     64            // bucketize blocks; each owns 1024 batch elements
#define NTILE   16            // 16 x 64-row tiles per relation (cap 1024 >= max cnt)

typedef __attribute__((ext_vector_type(8))) short bf16x8;
typedef __attribute__((ext_vector_type(4))) float f32x4;

__device__ __forceinline__ unsigned short f2bf(float x) {   // RNE f32->bf16
    unsigned u = __float_as_uint(x);
    u += 0x7fffu + ((u >> 16) & 1u);
    return (unsigned short)(u >> 16);
}

// ---- Kernel A: deterministic block-local counting sort --------------------
// 64 blocks x 256 threads x 4 elems. LDS histogram -> 128-wide LDS scan ->
// scatter into an exact 1024-slot segment bucket[bid][1024] (bijective: no
// caps, no global atomics, nothing needs pre-zeroing -> no memset node).
// Also emits hist[rel][blk] and lpfx[rel][blk] for kernel B's addressing.
// LDS-atomic rank order is run-varying, but each element's score depends only
// on its own (h,t,rel), so output VALUES are identical across runs.
__launch_bounds__(256)
__global__ void transr_bucket(const int* __restrict__ relation,
                              int* __restrict__ ws_hist,
                              int* __restrict__ ws_lpfx,
                              int* __restrict__ ws_bucket) {
    __shared__ int hist[NREL];
    __shared__ int scan[128];
    const int tid = threadIdx.x, bid = blockIdx.x;

    for (int r = tid; r < NREL; r += 256) hist[r] = 0;
    __syncthreads();

    const int4 v = ((const int4*)relation)[bid * 256 + tid];
    const int vals[4] = {v.x, v.y, v.z, v.w};
    int lr[4];
    #pragma unroll
    for (int k = 0; k < 4; ++k) lr[k] = atomicAdd(&hist[vals[k]], 1);
    __syncthreads();

    if (tid < 128) scan[tid] = (tid < NREL) ? hist[tid] : 0;
    __syncthreads();
    #pragma unroll
    for (int off = 1; off < 128; off <<= 1) {      // Hillis-Steele inclusive
        int t = 0;
        if (tid < 128 && tid >= off) t = scan[tid - off];
        __syncthreads();
        if (tid < 128) scan[tid] += t;
        __syncthreads();
    }

    const int i0 = (bid * 256 + tid) * 4;
    #pragma unroll
    for (int k = 0; k < 4; ++k) {
        const int rel = vals[k];
        ws_bucket[bid * 1024 + (scan[rel] - hist[rel]) + lr[k]] = i0 + k;
    }
    for (int r = tid; r < NREL; r += 256) {
        ws_hist[r * NBB + bid] = hist[r];
        ws_lpfx[r * NBB + bid] = scan[r] - hist[r];
    }
}

// ---- Kernel B: MFMA per-(relation, 64-row tile) — round-5-validated math --
__launch_bounds__(256)
__global__ void transr_compute(const int* __restrict__ head,
                               const int* __restrict__ tail,
                               const float* __restrict__ ent,
                               const float* __restrict__ remb,
                               const float* __restrict__ proj,
                               const int* __restrict__ ws_hist,
                               const int* __restrict__ ws_lpfx,
                               const int* __restrict__ ws_bucket,
                               float* __restrict__ out) {
    __shared__ unsigned short Abuf[64 * 64];   // D rows (bf16), XOR-swizzled slices
    __shared__ unsigned short Bbuf[64 * 64];   // P^T  (bf16), XOR-swizzled slices
    __shared__ float remb_s[64];
    __shared__ int   pfx_s[64];                // excl. prefix of hist[rel][blk]
    __shared__ int   lpfx_s[64];               // within-block segment offsets
    __shared__ int   bidx_s[64];
    __shared__ int   cnt_s;

    const int tid   = threadIdx.x;
    const int wid   = tid >> 6;
    const int lane  = tid & 63;
    const int rel   = blockIdx.y;
    const int start = blockIdx.x << 6;

    // wave 0: load this relation's per-block counts, 64-wide shfl prefix scan
    if (wid == 0) {
        int h = ws_hist[rel * NBB + lane];
        lpfx_s[lane] = ws_lpfx[rel * NBB + lane];
        const int own = h;
        #pragma unroll
        for (int m = 1; m < 64; m <<= 1) {
            int t = __shfl_up(h, m);
            if (lane >= m) h += t;
        }
        pfx_s[lane] = h - own;
        if (lane == 63) cnt_s = h;
    }

    // stage B^T: thread = (k = tid>>2, q = tid&3) reads P[k][q*16..+15]
    {
        const int k = tid >> 2, q = tid & 3;
        const float4* p4 = (const float4*)(proj + (size_t)rel * 4096 + k * 64 + q * 16);
        const int khi = k >> 3, klo = k & 7;
        #pragma unroll
        for (int m = 0; m < 4; ++m) {
            float4 v = p4[m];
            const float vv[4] = {v.x, v.y, v.z, v.w};
            #pragma unroll
            for (int j2 = 0; j2 < 4; ++j2) {
                const int n = q * 16 + m * 4 + j2;
                Bbuf[n * 64 + ((khi ^ (n & 7)) * 8) + klo] = f2bf(vv[j2]);
            }
        }
    }
    if (tid < 64) remb_s[tid] = remb[rel * 64 + tid];
    __syncthreads();

    const int cnt = cnt_s;
    if (start >= cnt) return;                 // empty tail tile (uniform exit)

    // ---- stage A: thread = (row = tid>>2, quarter q = tid&3)
    {
        const int row = tid >> 2, q = tid & 3;
        const int j  = start + row;
        const int jj = (j < cnt) ? j : (cnt - 1);
        int lo = 0;                           // last blk with pfx_s[blk] <= jj
        #pragma unroll
        for (int s = 32; s; s >>= 1) {
            const int c = lo + s;
            if (c < 64 && pfx_s[c] <= jj) lo = c;
        }
        const int b = ws_bucket[lo * 1024 + lpfx_s[lo] + (jj - pfx_s[lo])];
        if (q == 0) bidx_s[row] = b;
        const int h = head[b], t = tail[b];
        const float4* h4 = (const float4*)(ent + (size_t)h * 64) + q * 4;
        const float4* t4 = (const float4*)(ent + (size_t)t * 64) + q * 4;
        #pragma unroll
        for (int i = 0; i < 2; ++i) {
            unsigned short u[8];
            #pragma unroll
            for (int m = 0; m < 2; ++m) {
                float4 a = h4[i * 2 + m], c = t4[i * 2 + m];
                u[m * 4 + 0] = f2bf(a.x - c.x);
                u[m * 4 + 1] = f2bf(a.y - c.y);
                u[m * 4 + 2] = f2bf(a.z - c.z);
                u[m * 4 + 3] = f2bf(a.w - c.w);
            }
            const int slice = (q * 2 + i) ^ (row & 7);   // XOR swizzle
            *(bf16x8*)&Abuf[row * 64 + slice * 8] = *(bf16x8*)u;
        }
    }
    __syncthreads();

    // ---- MFMA: wave strip = rows wid*16..+15; 2 k-steps x 4 n-tiles
    const int arow = wid * 16 + (lane & 15);
    const int g    = lane >> 4;

    f32x4 acc[4];
    #pragma unroll
    for (int f = 0; f < 4; ++f) {
        const float rv = remb_s[f * 16 + (lane & 15)];   // fold remb into C init
        acc[f] = (f32x4){rv, rv, rv, rv};
    }
    #pragma unroll
    for (int s = 0; s < 2; ++s) {
        const int ks = g + s * 4;
        bf16x8 av = *(const bf16x8*)&Abuf[arow * 64 + ((ks ^ (arow & 7)) * 8)];
        #pragma unroll
        for (int f = 0; f < 4; ++f) {
            const int col = f * 16 + (lane & 15);
            bf16x8 bv = *(const bf16x8*)&Bbuf[col * 64 + ((ks ^ (col & 7)) * 8)];
            acc[f] = __builtin_amdgcn_mfma_f32_16x16x32_bf16(av, bv, acc[f], 0, 0, 0);
        }
    }

    // ---- epilogue: score = sum of squares; reduce across 16 col-lanes
    float ps[4];
    #pragma unroll
    for (int r = 0; r < 4; ++r)
        ps[r] = acc[0][r] * acc[0][r] + acc[1][r] * acc[1][r] +
                acc[2][r] * acc[2][r] + acc[3][r] * acc[3][r];
    #pragma unroll
    for (int m = 1; m < 16; m <<= 1) {
        #pragma unroll
        for (int r = 0; r < 4; ++r) ps[r] += __shfl_xor(ps[r], m, 64);
    }
    if ((lane & 15) == 0) {
        const int rowb = wid * 16 + g * 4;
        #pragma unroll
        for (int r = 0; r < 4; ++r) {
            const int j = start + rowb + r;
            if (j < cnt) out[bidx_s[rowb + r]] = ps[r];
        }
    }
}

extern "C" void kernel_launch(void* const* d_in, const int* in_sizes, int n_in,
                              void* d_out, int out_size, void* d_ws, size_t ws_size,
                              hipStream_t stream) {
    const int*   head     = (const int*)d_in[0];
    const int*   relation = (const int*)d_in[1];
    const int*   tail     = (const int*)d_in[2];
    const float* ent      = (const float*)d_in[3];
    const float* remb     = (const float*)d_in[4];
    const float* proj     = (const float*)d_in[5];
    float*       out      = (float*)d_out;

    // ws layout (all cells rewritten every call -> no zeroing needed):
    int* ws_hist   = (int*)d_ws;               // [100*64]  @ 0     (25.6 KB)
    int* ws_lpfx   = (int*)d_ws + 8192;        // [100*64]  @ 32 KB (25.6 KB)
    int* ws_bucket = (int*)d_ws + 16384;       // [64*1024] @ 64 KB (256 KB)

    transr_bucket<<<NBB, 256, 0, stream>>>(relation, ws_hist, ws_lpfx, ws_bucket);
    transr_compute<<<dim3(NTILE, NREL), 256, 0, stream>>>(
        head, tail, ent, remb, proj, ws_hist, ws_lpfx, ws_bucket, out);
}

// Round 8
// 21.053 us; speedup vs baseline: 1.8940x; 1.0792x over previous
//
#include <hip/hip_runtime.h>

#define BATCH   65536
#define NREL    100
#define NBB     64            // bucketize blocks; each owns 1024 batch elements
#define NTILE   16            // 16 x 64-row tiles per relation (cap 1024 >= max cnt)

typedef __attribute__((ext_vector_type(8))) short bf16x8;
typedef __attribute__((ext_vector_type(4))) float f32x4;

__device__ __forceinline__ unsigned short f2bf(float x) {   // RNE f32->bf16
    unsigned u = __float_as_uint(x);
    u += 0x7fffu + ((u >> 16) & 1u);
    return (unsigned short)(u >> 16);
}

// ---- Kernel A: prep = [blocks 0..63: counting sort] + [64..163: P->bf16] --
// Bucket part (validated round 7): LDS histogram -> 128-wide scan -> scatter
// into exact 1024-slot segment bucket[bid][1024]; emits hist/lpfx tables.
// Convert part: block 64+rel writes the EXACT swizzled bf16 LDS image of
// P[rel] into ws_pbf: img[n*64 + ((k>>3)^(n&7))*8 + (k&7)] = bf(P[k][n]).
// All ws cells rewritten every call -> no zeroing, no memset node.
__launch_bounds__(256)
__global__ void transr_prep(const int* __restrict__ relation,
                            const float* __restrict__ proj,
                            int* __restrict__ ws_hist,
                            int* __restrict__ ws_lpfx,
                            int* __restrict__ ws_bucket,
                            unsigned short* __restrict__ ws_pbf) {
    const int tid = threadIdx.x, bid = blockIdx.x;

    if (bid < NBB) {
        __shared__ int hist[NREL];
        __shared__ int scan[128];

        for (int r = tid; r < NREL; r += 256) hist[r] = 0;
        __syncthreads();

        const int4 v = ((const int4*)relation)[bid * 256 + tid];
        const int vals[4] = {v.x, v.y, v.z, v.w};
        int lr[4];
        #pragma unroll
        for (int k = 0; k < 4; ++k) lr[k] = atomicAdd(&hist[vals[k]], 1);
        __syncthreads();

        if (tid < 128) scan[tid] = (tid < NREL) ? hist[tid] : 0;
        __syncthreads();
        #pragma unroll
        for (int off = 1; off < 128; off <<= 1) {      // Hillis-Steele inclusive
            int t = 0;
            if (tid < 128 && tid >= off) t = scan[tid - off];
            __syncthreads();
            if (tid < 128) scan[tid] += t;
            __syncthreads();
        }

        const int i0 = (bid * 256 + tid) * 4;
        #pragma unroll
        for (int k = 0; k < 4; ++k) {
            const int rel = vals[k];
            ws_bucket[bid * 1024 + (scan[rel] - hist[rel]) + lr[k]] = i0 + k;
        }
        for (int r = tid; r < NREL; r += 256) {
            ws_hist[r * NBB + bid] = hist[r];
            ws_lpfx[r * NBB + bid] = scan[r] - hist[r];
        }
    } else {
        const int rel = bid - NBB;
        const int n = tid >> 2, q = tid & 3;
        const float* Pr = proj + (size_t)rel * 4096;
        unsigned short* dst = ws_pbf + (size_t)rel * 4096;
        #pragma unroll
        for (int kh = 0; kh < 2; ++kh) {
            const int khi = q * 2 + kh;
            unsigned short u[8];
            #pragma unroll
            for (int klo = 0; klo < 8; ++klo)
                u[klo] = f2bf(Pr[(khi * 8 + klo) * 64 + n]);
            *(bf16x8*)&dst[n * 64 + ((khi ^ (n & 7)) << 3)] = *(bf16x8*)u;
        }
    }
}

// ---- Kernel B: MFMA per-(relation, 64-row tile) — round-5-validated math --
// Changes vs round 7: early-exit BEFORE any staging; Bbuf staged by pure
// vectorized copy of the pre-swizzled bf16 image (32 B/thread); gather chain
// issued first so its latency overlaps the copy.
__launch_bounds__(256)
__global__ void transr_compute(const int* __restrict__ head,
                               const int* __restrict__ tail,
                               const float* __restrict__ ent,
                               const float* __restrict__ remb,
                               const int* __restrict__ ws_hist,
                               const int* __restrict__ ws_lpfx,
                               const int* __restrict__ ws_bucket,
                               const unsigned short* __restrict__ ws_pbf,
                               float* __restrict__ out) {
    __shared__ unsigned short Abuf[64 * 64];   // D rows (bf16), XOR-swizzled slices
    __shared__ unsigned short Bbuf[64 * 64];   // P^T  (bf16), pre-swizzled image
    __shared__ float remb_s[64];
    __shared__ int   pfx_s[64];                // excl. prefix of hist[rel][blk]
    __shared__ int   lpfx_s[64];               // within-block segment offsets
    __shared__ int   bidx_s[64];
    __shared__ int   cnt_s;

    const int tid   = threadIdx.x;
    const int wid   = tid >> 6;
    const int lane  = tid & 63;
    const int rel   = blockIdx.y;
    const int start = blockIdx.x << 6;

    // phase 0: wave 0 prefix-scans this relation's 64 per-block counts
    if (wid == 0) {
        int h = ws_hist[rel * NBB + lane];
        lpfx_s[lane] = ws_lpfx[rel * NBB + lane];
        const int own = h;
        #pragma unroll
        for (int m = 1; m < 64; m <<= 1) {
            int t = __shfl_up(h, m);
            if (lane >= m) h += t;
        }
        pfx_s[lane] = h - own;
        if (lane == 63) cnt_s = h;
    }
    if (tid < 64) remb_s[tid] = remb[rel * 64 + tid];
    __syncthreads();

    const int cnt = cnt_s;
    if (start >= cnt) return;                 // empty tail tile: exit pre-staging

    // phase 1a: stage A (long-latency gather chain issues first)
    {
        const int row = tid >> 2, q = tid & 3;
        const int j  = start + row;
        const int jj = (j < cnt) ? j : (cnt - 1);
        int lo = 0;                           // last blk with pfx_s[blk] <= jj
        #pragma unroll
        for (int s = 32; s; s >>= 1) {
            const int c = lo + s;
            if (c < 64 && pfx_s[c] <= jj) lo = c;
        }
        const int b = ws_bucket[lo * 1024 + lpfx_s[lo] + (jj - pfx_s[lo])];
        if (q == 0) bidx_s[row] = b;
        const int h = head[b], t = tail[b];
        const float4* h4 = (const float4*)(ent + (size_t)h * 64) + q * 4;
        const float4* t4 = (const float4*)(ent + (size_t)t * 64) + q * 4;
        #pragma unroll
        for (int i = 0; i < 2; ++i) {
            unsigned short u[8];
            #pragma unroll
            for (int m = 0; m < 2; ++m) {
                float4 a = h4[i * 2 + m], c = t4[i * 2 + m];
                u[m * 4 + 0] = f2bf(a.x - c.x);
                u[m * 4 + 1] = f2bf(a.y - c.y);
                u[m * 4 + 2] = f2bf(a.z - c.z);
                u[m * 4 + 3] = f2bf(a.w - c.w);
            }
            const int slice = (q * 2 + i) ^ (row & 7);   // XOR swizzle
            *(bf16x8*)&Abuf[row * 64 + slice * 8] = *(bf16x8*)u;
        }
    }
    // phase 1b: stage B = vectorized copy of pre-swizzled image (32 B/thread)
    {
        const uint4* src = (const uint4*)(ws_pbf + (size_t)rel * 4096) + tid * 2;
        uint4* dst = (uint4*)Bbuf + tid * 2;
        dst[0] = src[0];
        dst[1] = src[1];
    }
    __syncthreads();

    // ---- MFMA: wave strip = rows wid*16..+15; 2 k-steps x 4 n-tiles
    const int arow = wid * 16 + (lane & 15);
    const int g    = lane >> 4;

    f32x4 acc[4];
    #pragma unroll
    for (int f = 0; f < 4; ++f) {
        const float rv = remb_s[f * 16 + (lane & 15)];   // fold remb into C init
        acc[f] = (f32x4){rv, rv, rv, rv};
    }
    #pragma unroll
    for (int s = 0; s < 2; ++s) {
        const int ks = g + s * 4;
        bf16x8 av = *(const bf16x8*)&Abuf[arow * 64 + ((ks ^ (arow & 7)) * 8)];
        #pragma unroll
        for (int f = 0; f < 4; ++f) {
            const int col = f * 16 + (lane & 15);
            bf16x8 bv = *(const bf16x8*)&Bbuf[col * 64 + ((ks ^ (col & 7)) * 8)];
            acc[f] = __builtin_amdgcn_mfma_f32_16x16x32_bf16(av, bv, acc[f], 0, 0, 0);
        }
    }

    // ---- epilogue: score = sum of squares; reduce across 16 col-lanes
    float ps[4];
    #pragma unroll
    for (int r = 0; r < 4; ++r)
        ps[r] = acc[0][r] * acc[0][r] + acc[1][r] * acc[1][r] +
                acc[2][r] * acc[2][r] + acc[3][r] * acc[3][r];
    #pragma unroll
    for (int m = 1; m < 16; m <<= 1) {
        #pragma unroll
        for (int r = 0; r < 4; ++r) ps[r] += __shfl_xor(ps[r], m, 64);
    }
    if ((lane & 15) == 0) {
        const int rowb = wid * 16 + g * 4;
        #pragma unroll
        for (int r = 0; r < 4; ++r) {
            const int j = start + rowb + r;
            if (j < cnt) out[bidx_s[rowb + r]] = ps[r];
        }
    }
}

extern "C" void kernel_launch(void* const* d_in, const int* in_sizes, int n_in,
                              void* d_out, int out_size, void* d_ws, size_t ws_size,
                              hipStream_t stream) {
    const int*   head     = (const int*)d_in[0];
    const int*   relation = (const int*)d_in[1];
    const int*   tail     = (const int*)d_in[2];
    const float* ent      = (const float*)d_in[3];
    const float* remb     = (const float*)d_in[4];
    const float* proj     = (const float*)d_in[5];
    float*       out      = (float*)d_out;

    // ws layout (every read cell rewritten each call -> no zeroing needed):
    int* ws_hist   = (int*)d_ws;               // [100*64]  @ 0     (25.6 KB)
    int* ws_lpfx   = (int*)d_ws + 8192;        // [100*64]  @ 32 KB (25.6 KB)
    int* ws_bucket = (int*)d_ws + 16384;       // [64*1024] @ 64 KB (256 KB)
    unsigned short* ws_pbf =
        (unsigned short*)((char*)d_ws + 512 * 1024);   // [100*4096] @ 512 KB (800 KB)

    transr_prep<<<NBB + NREL, 256, 0, stream>>>(relation, proj,
                                                ws_hist, ws_lpfx, ws_bucket, ws_pbf);
    transr_compute<<<dim3(NTILE, NREL), 256, 0, stream>>>(
        head, tail, ent, remb, ws_hist, ws_lpfx, ws_bucket, ws_pbf, out);
}